// Round 2
// baseline (301.720 us; speedup 1.0000x reference)
//
#include <hip/hip_runtime.h>
#include <stdint.h>

// ---------------- problem constants ----------------
#define NP   250000
#define NA   10000
#define NBLK 5
#define NL   20            // 5 blocks x (2 iW + 2 oW) layers
#define BLOB_W_BYTES 16384               // 128x128 fp8 e4m3, row=out-feature, XOR-swizzled
#define BLOB_BYTES   16896               // + 128 fp32 folded biases (512 B)

#define LOG2E 1.4426950408889634f
#define LN2   0.6931471805599453f

typedef float  f32x4  __attribute__((ext_vector_type(4)));
typedef float  f32x2  __attribute__((ext_vector_type(2)));
typedef unsigned short ushort_t;
typedef unsigned int   uint_t;
typedef int4  i4_ma __attribute__((may_alias));
typedef uint2 u2_ma __attribute__((may_alias));
typedef uint_t u1_ma __attribute__((may_alias));

// raw single-instruction transcendentals (v_exp_f32 / v_log_f32); args bounded
#if __has_builtin(__builtin_amdgcn_exp2f)
#define FEXP2(x) __builtin_amdgcn_exp2f(x)
#else
#define FEXP2(x) exp2f(x)
#endif

// ---------------- static device scratch ----------------
__device__ uint8_t g_blob[NL * BLOB_BYTES];   // swizzled fp8 weights + folded f32 biases
__device__ float   g_outs[NBLK * NA * 2];     // per-block per-atom segment sums
__device__ float   g_nh[1];
__device__ unsigned g_done;
__device__ float   g_Rf[NA * 3];
__device__ float   g_oWfF[NBLK * 128 * 2];    // ln2-prescaled head weights
__device__ float   g_oBfF[NBLK * 2];          // head biases (unmodified)
__device__ float   g_scF[190];
__device__ float   g_shF[190];
// ssp piecewise-LINEAR LUT: u(t) = log2(0.5 + 2^t), t in [-15,17), 512 bins
// (delta = 1/16). Entry i = {u(x_i), u(x_{i+1})-u(x_i)}. Interp err <= 8.4e-5
// absolute — an order of magnitude under the fp8 e4m3 quantization step, so
// accuracy matches the exact-transcendental baseline. (Round-1 lesson: a
// nearest-bin table at delta=1/64 had ~4e-3 abs error at u~0 where the
// activation mass sits -> nhloss blew up 1.8 vs 0.455.)
__device__ float   g_lutI[1024];              // 512 x {base, slope}

static __device__ __forceinline__ float bf2f(ushort_t u) {
    return __uint_as_float(((uint_t)u) << 16);
}
// e4m3fn (OCP) encoder — fallback only
static __device__ uint8_t f2fp8(float f) {
    uint_t u = __float_as_uint(f);
    uint8_t s = (uint8_t)((u >> 24) & 0x80);
    float af = fabsf(f);
    if (af != af) return (uint8_t)(s | 0x7F);
    if (af > 448.0f) return (uint8_t)(s | 0x7E);
    int e = (int)((u >> 23) & 0xFF) - 127;
    uint_t m = u & 0x7FFFFFu;
    if (e >= -6) {
        uint_t mant = m >> 20;
        uint_t rest = m & 0xFFFFFu;
        if (rest > 0x80000u || (rest == 0x80000u && (mant & 1u))) mant++;
        uint_t ee = (uint_t)(e + 7);
        if (mant == 8u) { mant = 0u; ee++; }
        if (ee > 15u || (ee == 15u && mant > 6u)) return (uint8_t)(s | 0x7E);
        return (uint8_t)(s | (ee << 3) | mant);
    }
    int qq = (int)rintf(af * 512.0f);      // subnormal: grid 2^-9
    if (qq > 7) return (uint8_t)(s | 0x08);
    return (uint8_t)(s | (uint_t)qq);
}
// pack 2 f32 -> 2 fp8 bytes into low/high half of a dword (HI = immediate)
template <bool HI>
static __device__ __forceinline__ int cvtpk2(float a, float b, int old) {
#if __has_builtin(__builtin_amdgcn_cvt_pk_fp8_f32)
    return __builtin_amdgcn_cvt_pk_fp8_f32(a, b, old, HI);
#else
    int p = (int)f2fp8(a) | ((int)f2fp8(b) << 8);
    return HI ? (int)((old & 0x0000FFFF) | ((uint_t)p << 16))
              : (int)((old & 0xFFFF0000) | (uint_t)p);
#endif
}
static __device__ __forceinline__ long u2l(u2_ma v) {
    union { u2_ma u; long l; } x; x.u = v; return x.l;
}
// interpolated ssp: ~5 full-rate VALU + ds_read_b64, replaces exp2+log2
static __device__ __forceinline__ float ssp_lut(const f32x2* lut, float t) {
#if __has_builtin(__builtin_amdgcn_fmed3f)
    float f = __builtin_amdgcn_fmed3f(fmaf(t, 16.0f, 240.0f), 0.0f, 511.0f);
#else
    float f = fminf(fmaxf(fmaf(t, 16.0f, 240.0f), 0.0f), 511.0f);
#endif
    int i = (int)f;                 // trunc == floor (f >= 0)
    float fr = f - (float)i;
    f32x2 bs = lut[i];
    return fmaf(fr, bs[1], bs[0]);
}

// dtype auto-detection (validated round 4: inputs are f32; keep as insurance)
static __device__ __forceinline__ bool detect_is_f32(const ushort_t* probe) {
    __shared__ int flag;
    if (threadIdx.x == 0) flag = 0;
    __syncthreads();
    if (threadIdx.x < 256) {
        float v = fabsf(bf2f(probe[2 * threadIdx.x]));
        if (!(v <= 64.0f)) flag = 1;
    }
    __syncthreads();
    return flag != 0;
}
static __device__ __forceinline__ float in_elt(const void* p, int i, bool isf32) {
    return isf32 ? ((const float*)p)[i] : bf2f(((const ushort_t*)p)[i]);
}

// ---------------- merged prep: weights (blocks 0..79) + misc (blocks 80..470) --------
// blob[L]: row m (out-feature) * 128 fp8 bytes; chunk c=k>>3 (8 B) at
// m*128 + 8*((k>>3)^(m&15)) + (k&7). Dword-wise with HW cvt_pk (RNE).
// L==0: W prescaled by log2e. bias = b*log2e - 1.
__global__ void prep_kernel(const void* __restrict__ iW, const void* __restrict__ iB,
                            const void* __restrict__ oW, const void* __restrict__ oB,
                            const void* __restrict__ R, const void* __restrict__ oWf,
                            const void* __restrict__ oBf, const void* __restrict__ scales,
                            const void* __restrict__ shifts)
{
    const bool isf32 = detect_is_f32((const ushort_t*)iW);
    if (blockIdx.x < 80) {
        const int L = blockIdx.x >> 2;      // 0..19
        const int qr = blockIdx.x & 3;      // dword-quarter
        const int b = L >> 2, li = L & 3;
        const void* srcW = (li < 2) ? iW : oW;
        const void* srcB = (li < 2) ? iB : oB;
        const int lyr = (li < 2) ? (b * 2 + li) : (b * 2 + li - 2);
        const int wofs = lyr * 16384;
        const int bofs = lyr * 128;
        uint8_t* blob = g_blob + (size_t)L * BLOB_BYTES;
        uint_t* dw = (uint_t*)blob;
        float*  db = (float*)(blob + BLOB_W_BYTES);
        const float sc = (L == 0) ? LOG2E : 1.0f;
        for (int t = threadIdx.x; t < 1024; t += blockDim.x) {
            int d = qr * 1024 + t;          // dword id: n = d&127, k-group kg = d>>7
            int n = d & 127, kg = d >> 7;   // k0 = kg*4
            float w0 = sc * in_elt(srcW, wofs + (kg * 4 + 0) * 128 + n, isf32);
            float w1 = sc * in_elt(srcW, wofs + (kg * 4 + 1) * 128 + n, isf32);
            float w2 = sc * in_elt(srcW, wofs + (kg * 4 + 2) * 128 + n, isf32);
            float w3 = sc * in_elt(srcW, wofs + (kg * 4 + 3) * 128 + n, isf32);
            int w = cvtpk2<false>(w0, w1, 0);
            w = cvtpk2<true>(w2, w3, w);
            dw[n * 32 + 2 * ((kg >> 1) ^ (n & 15)) + (kg & 1)] = (uint_t)w;
        }
        if (qr == 0)
            for (int m = threadIdx.x; m < 128; m += blockDim.x)
                db[m] = in_elt(srcB, bofs + m, isf32) * LOG2E - 1.0f;
    } else {
        const int t = (blockIdx.x - 80) * 256 + threadIdx.x;
        if (t < NBLK * NA * 2) g_outs[t] = 0.0f;
        if (t == 0) { g_nh[0] = 0.0f; g_done = 0u; }
        if (t < NA * 3)      g_Rf[t]   = in_elt(R, t, isf32);
        if (t < NBLK * 256)  g_oWfF[t] = LN2 * in_elt(oWf, t, isf32);
        if (t < NBLK * 2)    g_oBfF[t] = in_elt(oBf, t, isf32);
        if (t < 190)         g_scF[t]  = in_elt(scales, t, isf32);
        if (t < 190)         g_shF[t]  = in_elt(shifts, t, isf32);
        // ---- ssp linear-interp LUT build: 512 bins over [-15,17), delta=1/16 ----
        if (t < 512) {
            float x0 = -15.0f + (float)t * 0.0625f;
            float u0 = log2f(0.5f + exp2f(x0));
            float u1 = log2f(0.5f + exp2f(x0 + 0.0625f));
            g_lutI[2 * t]     = u0;
            g_lutI[2 * t + 1] = u1 - u0;
        }
    }
}

// ---------------- fused per-pair MLP, fp8 path, wg-shared weights ----------------
// ROUND-12 VALIDATED SHAPE (209 us): wg = 256 = 4 waves x 32 pairs. Per layer:
// barrier -> cooperative 16 KB weight stage -> barrier -> compute from LDS
// A-frags + wave-private 4 KB in-place act region. x2 carried across li2/li3
// in 8 VGPRs. LDS = 16 KB W + 4 x 4 KB act + 4 KB interp LUT = 36 KB.
// launch_bounds(256,3): 170-reg cap; no spill.
// THIS ROUND: ssp transcendentals (exp2+log2 per activation ~= 87% of the
// measured 71% VALUBusy) replaced by interpolated LDS LUT (5 full-rate VALU
// + ds_read_b64, abs err <= 8.4e-5 << fp8 step). Predicted: VALU 71->~50%.
__global__ __launch_bounds__(256, 3)
void pairs_mlp_kernel(const int* __restrict__ idx_i,
                      const int* __restrict__ idx_j,
                      float* __restrict__ out_rij)       // d_out + 20000 (f32)
{
    __shared__ i4_ma w_lds[1024];            // 16 KB: fp8 weight blob of layer L
    __shared__ u2_ma act_all[4 * 512];       // 4 waves x (32 rows x 16 chunks of 8B)
    __shared__ float lutI[1024];             // 4 KB: {base,slope} x 512

    // stage LUT (writes complete before the first layer barrier)
#pragma unroll
    for (int i = 0; i < 4; ++i) lutI[threadIdx.x + 256 * i] = g_lutI[threadIdx.x + 256 * i];

    const int wave = threadIdx.x >> 6;
    const int lane = threadIdx.x & 63;
    u2_ma* act = act_all + wave * 512;
    const u2_ma* wl2 = (const u2_ma*)w_lds;
    const f32x2* lut = (const f32x2*)lutI;

    const int pp = lane & 31;           // pair owned (both half-waves mirror)
    const int p0 = blockIdx.x * 128 + wave * 32;
    const int p = p0 + pp;
    const bool valid = (p < NP);

    // ---- phase 0: rij + radial basis, built DIRECTLY into fp8 B-frag regs ----
    int ai = 0, aj = 0;
    if (valid) { ai = idx_i[p]; aj = idx_j[p]; }
    float xi0 = g_Rf[3 * ai + 0], xi1 = g_Rf[3 * ai + 1], xi2 = g_Rf[3 * ai + 2];
    float xj0 = g_Rf[3 * aj + 0], xj1 = g_Rf[3 * aj + 1], xj2 = g_Rf[3 * aj + 2];
    float dx = xj0 - xi0, dy = xj1 - xi1, dz = xj2 - xi2;
    float rij = sqrtf(dx * dx + dy * dy + dz * dz + 1e-12f);
    if (lane < 32 && valid) out_rij[p] = rij;

    float fcut = 0.0f;
    if (valid && rij < 10.0f) {
        float xc = rij * 0.1f;
        float x3 = xc * xc * xc;
        fcut = 1.0f + x3 * (-10.0f + xc * (15.0f - 6.0f * xc));
    }
    const float mu0 = 4.5399929762484854e-05f;
    const float dmu = (1.0f - mu0) / 127.0f;
    const float wc = (2.0f / 128.0f) * (1.0f - mu0);
    const float NW2 = -(1.0f / (wc * wc)) * LOG2E;
    float er = FEXP2(-rij * LOG2E);

    const int q = lane >> 4;        // quad
    const int l15 = lane & 15;
    const int aseg = valid ? ai : -1;   // sentinel: invalid pairs never merge/fire

    // B-frag carry regs: bfrX[nt][kt] = x[pair nt*16+l15][k=kt*32+q*8 .. +7] fp8
    u2_ma bfrX[2][4];
    {
        float er_n[2], fc_n[2];
        er_n[0] = __shfl(er, l15, 64);      fc_n[0] = __shfl(fcut, l15, 64);
        er_n[1] = __shfl(er, 16 + l15, 64); fc_n[1] = __shfl(fcut, 16 + l15, 64);
#pragma unroll
        for (int nt = 0; nt < 2; ++nt)
#pragma unroll
            for (int kt = 0; kt < 4; ++kt) {
                float v[8];
#pragma unroll
                for (int jj = 0; jj < 8; ++jj) {
                    int g = kt * 32 + q * 8 + jj;
                    float mu = mu0 + (float)g * dmu;
                    float e0 = er_n[nt] - mu;
                    v[jj] = fc_n[nt] * FEXP2(NW2 * e0 * e0);
                }
                int w0 = cvtpk2<false>(v[0], v[1], 0);
                w0 = cvtpk2<true>(v[2], v[3], w0);
                int w1 = cvtpk2<false>(v[4], v[5], 0);
                w1 = cvtpk2<true>(v[6], v[7], w1);
                bfrX[nt][kt].x = (uint_t)w0;
                bfrX[nt][kt].y = (uint_t)w1;
            }
    }

    for (int blk = 0; blk < NBLK; ++blk) {
#pragma unroll
        for (int li = 0; li < 4; ++li) {
            const int L = blk * 4 + li;
            const i4_ma* gW = (const i4_ma*)(g_blob + (size_t)L * BLOB_BYTES);
            const float* bb = (const float*)(g_blob + (size_t)L * BLOB_BYTES + BLOB_W_BYTES);

            // ---- cooperative weight staging (all 4 waves) ----
            __syncthreads();              // everyone done reading W_{L-1}
#pragma unroll
            for (int it = 0; it < 4; ++it)
                w_lds[threadIdx.x + it * 256] = gW[threadIdx.x + it * 256];
            __syncthreads();

            // acc initialized to folded bias (b*log2e - 1)
            f32x4 acc[2][8];
#pragma unroll
            for (int mt = 0; mt < 8; ++mt) {
                const f32x4 bias = *(const f32x4*)(bb + mt * 16 + q * 4);
                acc[0][mt] = bias;
                acc[1][mt] = bias;
            }
#pragma unroll
            for (int kt = 0; kt < 4; ++kt) {
                const int cc = kt * 4 + q;
                u2_ma b0, b1;
                if (li == 0) {
                    b0 = bfrX[0][kt];
                    b1 = bfrX[1][kt];
                } else {
                    b0 = act[(l15) * 16 + (cc ^ l15)];
                    b1 = act[(16 + l15) * 16 + (cc ^ l15)];
                    if (li == 2) { bfrX[0][kt] = b0; bfrX[1][kt] = b1; }  // carry x
                }
                const long lb0 = u2l(b0), lb1 = u2l(b1);
#pragma unroll
                for (int mt = 0; mt < 8; ++mt) {
                    const long la = u2l(wl2[(mt * 16 + l15) * 16 + (cc ^ l15)]);
                    acc[0][mt] = __builtin_amdgcn_mfma_f32_16x16x32_fp8_fp8(
                        la, lb0, acc[0][mt], 0, 0, 0);
                    acc[1][mt] = __builtin_amdgcn_mfma_f32_16x16x32_fp8_fp8(
                        la, lb1, acc[1][mt], 0, 0, 0);
                }
            }

            if (li < 3) {
                // ssp via interp LUT + fp8 pack + in-place LDS write
                // (wave-private region; all this layer's act ds_reads precede
                // these writes in program order; LUT region is disjoint)
#pragma unroll
                for (int mt = 0; mt < 8; ++mt) {
                    const int c = mt * 2 + (q >> 1);   // feature chunk (8 fp8)
#pragma unroll
                    for (int nt = 0; nt < 2; ++nt) {
                        float u0 = ssp_lut(lut, acc[nt][mt][0]);
                        float u1 = ssp_lut(lut, acc[nt][mt][1]);
                        float u2 = ssp_lut(lut, acc[nt][mt][2]);
                        float u3 = ssp_lut(lut, acc[nt][mt][3]);
                        int w = cvtpk2<false>(u0, u1, 0);
                        w = cvtpk2<true>(u2, u3, w);
                        const int rp = nt * 16 + l15;
                        ((u1_ma*)&act[rp * 16 + (c ^ (rp & 15))])[q & 1] = (uint_t)w;
                    }
                }
            } else {
                // head: out_e = u3 @ (ln2*oWf) + oBf, then sorted-segment reduction
                const float* hw = g_oWfF + blk * 256;
                const float ob0 = g_oBfF[blk * 2 + 0];
                const float ob1 = g_oBfF[blk * 2 + 1];
                float hs[2][2];
#pragma unroll
                for (int nt = 0; nt < 2; ++nt) {
                    float h0 = 0.f, h1 = 0.f;
#pragma unroll
                    for (int mt = 0; mt < 8; ++mt) {
#pragma unroll
                        for (int rr = 0; rr < 4; ++rr) {
                            float u = ssp_lut(lut, acc[nt][mt][rr]);
                            const int f = mt * 16 + q * 4 + rr;
                            h0 = fmaf(u, hw[f * 2 + 0], h0);
                            h1 = fmaf(u, hw[f * 2 + 1], h1);
                        }
                    }
                    h0 += __shfl_xor(h0, 16, 64);
                    h0 += __shfl_xor(h0, 32, 64);
                    h1 += __shfl_xor(h1, 16, 64);
                    h1 += __shfl_xor(h1, 32, 64);
                    hs[nt][0] = h0; hs[nt][1] = h1;
                }
                float c0v = (pp < 16) ? hs[0][0] : hs[1][0];
                float c1v = (pp < 16) ? hs[0][1] : hs[1][1];
                c0v += ob0; c1v += ob1;
                // segmented inclusive scan over the 32 sorted pairs (runs contiguous)
#pragma unroll
                for (int d = 1; d < 32; d <<= 1) {
                    float t0 = __shfl_up(c0v, d, 64);
                    float t1 = __shfl_up(c1v, d, 64);
                    int   an = __shfl_up(aseg, d, 64);
                    if (pp >= d && an == aseg) { c0v += t0; c1v += t1; }
                }
                int ain = __shfl_down(aseg, 1, 64);
                bool tail = (pp == 31) || (ain != aseg);
                if (lane < 32 && valid && tail) {
                    atomicAdd(&g_outs[(blk * NA + aseg) * 2 + 0], c0v);
                    atomicAdd(&g_outs[(blk * NA + aseg) * 2 + 1], c1v);
                }
            }
        }
    }
}

// ---------------- finalize: scale/shift + nhloss (last-block writes nh) ----------
__global__ void finalize_kernel(const int* __restrict__ Z,
                                float* __restrict__ out_atoms,   // d_out (f32)
                                float* __restrict__ out_nh)
{
    __shared__ float red[256];
    const int a = blockIdx.x * 256 + threadIdx.x;
    float s = 0.f;
    if (a < NA) {
        float v[NBLK][2];
        float t0 = 0.f, t1 = 0.f;
#pragma unroll
        for (int b = 0; b < NBLK; ++b) {
            v[b][0] = g_outs[(b * NA + a) * 2 + 0];
            v[b][1] = g_outs[(b * NA + a) * 2 + 1];
            t0 += v[b][0]; t1 += v[b][1];
        }
        const int z = Z[a];
        out_atoms[a * 2 + 0] = t0 * g_scF[z]      + g_shF[z];
        out_atoms[a * 2 + 1] = t1 * g_scF[95 + z] + g_shF[95 + z];
#pragma unroll
        for (int b = 1; b < NBLK; ++b)
#pragma unroll
            for (int o = 0; o < 2; ++o) {
                float x2 = v[b][o] * v[b][o];
                float p2 = v[b - 1][o] * v[b - 1][o];
                s += x2 / (x2 + p2 + 1e-7f);
            }
    }
    red[threadIdx.x] = s;
    __syncthreads();
    for (int st = 128; st > 0; st >>= 1) {
        if (threadIdx.x < st) red[threadIdx.x] += red[threadIdx.x + st];
        __syncthreads();
    }
    if (threadIdx.x == 0) {
        atomicAdd(&g_nh[0], red[0]);
        __threadfence();
        unsigned old = atomicAdd(&g_done, 1u);
        if (old == gridDim.x - 1) {
            float v = atomicAdd(&g_nh[0], 0.0f);   // device-scope coherent read
            out_nh[0] = v * (1.0f / 20000.0f);
        }
    }
}

// ---------------- launch ----------------
extern "C" void kernel_launch(void* const* d_in, const int* in_sizes, int n_in,
                              void* d_out, int out_size, void* d_ws, size_t ws_size,
                              hipStream_t stream)
{
    const int* Z     = (const int*)d_in[0];
    const void* R    = d_in[1];
    const int* idx_i = (const int*)d_in[2];
    const int* idx_j = (const int*)d_in[3];
    const void* iW   = d_in[4];
    const void* iB   = d_in[5];
    const void* oW   = d_in[6];
    const void* oB   = d_in[7];
    const void* oWf  = d_in[8];
    const void* oBf  = d_in[9];
    const void* scales = d_in[10];
    const void* shifts = d_in[11];

    float* out_f = (float*)d_out;   // [0,20000): outputs  [20000,270000): rij  [270000]: nhloss

    prep_kernel<<<80 + 391, 256, 0, stream>>>(iW, iB, oW, oB, R, oWf, oBf, scales, shifts);
    pairs_mlp_kernel<<<(NP + 127) / 128, 256, 0, stream>>>(idx_i, idx_j, out_f + 2 * NA);
    finalize_kernel<<<(NA + 255) / 256, 256, 0, stream>>>(Z, out_f, out_f + 2 * NA + NP);
}

// Round 3
// 276.043 us; speedup vs baseline: 1.0930x; 1.0930x over previous
//
#include <hip/hip_runtime.h>
#include <stdint.h>

// ---------------- problem constants ----------------
#define NP   250000
#define NA   10000
#define NBLK 5
#define NL   20            // 5 blocks x (2 iW + 2 oW) layers
#define BLOB_W_BYTES 16384               // 128x128 fp8 e4m3, row=out-feature, XOR-swizzled
#define BLOB_BYTES   16896               // + 128 fp32 folded biases (512 B)

#define LOG2E 1.4426950408889634f
#define LN2   0.6931471805599453f

typedef float  f32x4  __attribute__((ext_vector_type(4)));
typedef unsigned short ushort_t;
typedef unsigned int   uint_t;
typedef int4  i4_ma __attribute__((may_alias));
typedef uint2 u2_ma __attribute__((may_alias));
typedef uint_t u1_ma __attribute__((may_alias));

// compiler-level memory fence: pins issue order of loads/stages around barriers
#define FENCE() asm volatile("" ::: "memory")

// raw single-instruction transcendentals (v_exp_f32 / v_log_f32); args bounded.
// ROUND-2 LESSON: these are effectively FULL-RATE on gfx950 — an LDS-LUT
// replacement (interp, 5 VALU + ds_read) was 40 us SLOWER. Keep the trans.
#if __has_builtin(__builtin_amdgcn_exp2f)
#define FEXP2(x) __builtin_amdgcn_exp2f(x)
#else
#define FEXP2(x) exp2f(x)
#endif
#if __has_builtin(__builtin_amdgcn_logf)
#define FLOG2(x) __builtin_amdgcn_logf(x)
#else
#define FLOG2(x) log2f(x)
#endif

// ---------------- static device scratch ----------------
__device__ uint8_t g_blob[NL * BLOB_BYTES];   // swizzled fp8 weights + folded f32 biases
__device__ float   g_outs[NBLK * NA * 2];     // per-block per-atom segment sums
__device__ float   g_nh[1];
__device__ unsigned g_done;
__device__ float   g_Rf[NA * 3];
__device__ float   g_oWfF[NBLK * 128 * 2];    // ln2-prescaled head weights
__device__ float   g_oBfF[NBLK * 2];          // head biases (unmodified)
__device__ float   g_scF[190];
__device__ float   g_shF[190];

static __device__ __forceinline__ float bf2f(ushort_t u) {
    return __uint_as_float(((uint_t)u) << 16);
}
// e4m3fn (OCP) encoder — fallback only
static __device__ uint8_t f2fp8(float f) {
    uint_t u = __float_as_uint(f);
    uint8_t s = (uint8_t)((u >> 24) & 0x80);
    float af = fabsf(f);
    if (af != af) return (uint8_t)(s | 0x7F);
    if (af > 448.0f) return (uint8_t)(s | 0x7E);
    int e = (int)((u >> 23) & 0xFF) - 127;
    uint_t m = u & 0x7FFFFFu;
    if (e >= -6) {
        uint_t mant = m >> 20;
        uint_t rest = m & 0xFFFFFu;
        if (rest > 0x80000u || (rest == 0x80000u && (mant & 1u))) mant++;
        uint_t ee = (uint_t)(e + 7);
        if (mant == 8u) { mant = 0u; ee++; }
        if (ee > 15u || (ee == 15u && mant > 6u)) return (uint8_t)(s | 0x7E);
        return (uint8_t)(s | (ee << 3) | mant);
    }
    int qq = (int)rintf(af * 512.0f);      // subnormal: grid 2^-9
    if (qq > 7) return (uint8_t)(s | 0x08);
    return (uint8_t)(s | (uint_t)qq);
}
// pack 2 f32 -> 2 fp8 bytes into low/high half of a dword (HI = immediate)
template <bool HI>
static __device__ __forceinline__ int cvtpk2(float a, float b, int old) {
#if __has_builtin(__builtin_amdgcn_cvt_pk_fp8_f32)
    return __builtin_amdgcn_cvt_pk_fp8_f32(a, b, old, HI);
#else
    int p = (int)f2fp8(a) | ((int)f2fp8(b) << 8);
    return HI ? (int)((old & 0x0000FFFF) | ((uint_t)p << 16))
              : (int)((old & 0xFFFF0000) | (uint_t)p);
#endif
}
static __device__ __forceinline__ long u2l(u2_ma v) {
    union { u2_ma u; long l; } x; x.u = v; return x.l;
}
// stored activation: u = y/ln2 = log2(0.5 + 2^(t-1)); -1 folded into bias.
static __device__ __forceinline__ float ssp_u(float accv) {
    return FLOG2(0.5f + FEXP2(accv));
}

// async weight stage: 16 KB blob of layer L -> LDS buffer, 4 x global_load_lds
// width=16 per thread. LDS dest is wave-uniform base + lane*16 (linear order
// matches the linear global source). Tracked by vmcnt only.
static __device__ __forceinline__ void stage_w(int L, i4_ma* dst) {
    const uint8_t* gsrc = g_blob + (size_t)L * BLOB_BYTES;
    const int wave = threadIdx.x >> 6;
#pragma unroll
    for (int it = 0; it < 4; ++it) {
        const uint32_t* gp = (const uint32_t*)(gsrc + (((size_t)(it * 256) + threadIdx.x) << 4));
        uint32_t* lp = (uint32_t*)&dst[it * 256 + wave * 64];
        __builtin_amdgcn_global_load_lds(
            (const __attribute__((address_space(1))) uint32_t*)gp,
            (__attribute__((address_space(3))) uint32_t*)lp,
            16, 0, 0);
    }
}
// bias prefetch into VGPRs (8 x global_load_dwordx4). Issued BEFORE each
// stage_w so the vmcnt FIFO never force-drains the weight prefetch.
static __device__ __forceinline__ void load_bias(f32x4* bv, int L, int q) {
    const float* nb = (const float*)(g_blob + (size_t)L * BLOB_BYTES + BLOB_W_BYTES);
#pragma unroll
    for (int mt = 0; mt < 8; ++mt)
        bv[mt] = *(const f32x4*)(nb + mt * 16 + q * 4);
}

// dtype auto-detection (validated round 4: inputs are f32; keep as insurance)
static __device__ __forceinline__ bool detect_is_f32(const ushort_t* probe) {
    __shared__ int flag;
    if (threadIdx.x == 0) flag = 0;
    __syncthreads();
    if (threadIdx.x < 256) {
        float v = fabsf(bf2f(probe[2 * threadIdx.x]));
        if (!(v <= 64.0f)) flag = 1;
    }
    __syncthreads();
    return flag != 0;
}
static __device__ __forceinline__ float in_elt(const void* p, int i, bool isf32) {
    return isf32 ? ((const float*)p)[i] : bf2f(((const ushort_t*)p)[i]);
}

// ---------------- merged prep: weights (blocks 0..79) + misc (blocks 80..470) --------
// blob[L]: row m (out-feature) * 128 fp8 bytes; chunk c=k>>3 (8 B) at
// m*128 + 8*((k>>3)^(m&15)) + (k&7). Dword-wise with HW cvt_pk (RNE).
// L==0: W prescaled by log2e. bias = b*log2e - 1.
__global__ void prep_kernel(const void* __restrict__ iW, const void* __restrict__ iB,
                            const void* __restrict__ oW, const void* __restrict__ oB,
                            const void* __restrict__ R, const void* __restrict__ oWf,
                            const void* __restrict__ oBf, const void* __restrict__ scales,
                            const void* __restrict__ shifts)
{
    const bool isf32 = detect_is_f32((const ushort_t*)iW);
    if (blockIdx.x < 80) {
        const int L = blockIdx.x >> 2;      // 0..19
        const int qr = blockIdx.x & 3;      // dword-quarter
        const int b = L >> 2, li = L & 3;
        const void* srcW = (li < 2) ? iW : oW;
        const void* srcB = (li < 2) ? iB : oB;
        const int lyr = (li < 2) ? (b * 2 + li) : (b * 2 + li - 2);
        const int wofs = lyr * 16384;
        const int bofs = lyr * 128;
        uint8_t* blob = g_blob + (size_t)L * BLOB_BYTES;
        uint_t* dw = (uint_t*)blob;
        float*  db = (float*)(blob + BLOB_W_BYTES);
        const float sc = (L == 0) ? LOG2E : 1.0f;
        for (int t = threadIdx.x; t < 1024; t += blockDim.x) {
            int d = qr * 1024 + t;          // dword id: n = d&127, k-group kg = d>>7
            int n = d & 127, kg = d >> 7;   // k0 = kg*4
            float w0 = sc * in_elt(srcW, wofs + (kg * 4 + 0) * 128 + n, isf32);
            float w1 = sc * in_elt(srcW, wofs + (kg * 4 + 1) * 128 + n, isf32);
            float w2 = sc * in_elt(srcW, wofs + (kg * 4 + 2) * 128 + n, isf32);
            float w3 = sc * in_elt(srcW, wofs + (kg * 4 + 3) * 128 + n, isf32);
            int w = cvtpk2<false>(w0, w1, 0);
            w = cvtpk2<true>(w2, w3, w);
            dw[n * 32 + 2 * ((kg >> 1) ^ (n & 15)) + (kg & 1)] = (uint_t)w;
        }
        if (qr == 0)
            for (int m = threadIdx.x; m < 128; m += blockDim.x)
                db[m] = in_elt(srcB, bofs + m, isf32) * LOG2E - 1.0f;
    } else {
        const int t = (blockIdx.x - 80) * 256 + threadIdx.x;
        if (t < NBLK * NA * 2) g_outs[t] = 0.0f;
        if (t == 0) { g_nh[0] = 0.0f; g_done = 0u; }
        if (t < NA * 3)      g_Rf[t]   = in_elt(R, t, isf32);
        if (t < NBLK * 256)  g_oWfF[t] = LN2 * in_elt(oWf, t, isf32);
        if (t < NBLK * 2)    g_oBfF[t] = in_elt(oBf, t, isf32);
        if (t < 190)         g_scF[t]  = in_elt(scales, t, isf32);
        if (t < 190)         g_shF[t]  = in_elt(shifts, t, isf32);
    }
}

// ---------------- fused per-pair MLP, fp8 path, wg-shared weights ----------------
// ROUND-12 VALIDATED SHAPE: wg = 256 = 4 waves x 32 pairs; per-wave 4 KB
// in-place act region; x2 carried across li2/li3 in 8 VGPRs.
// THIS ROUND (stall attack): counters showed 34% MFMA + ~37% VALU + ~29%
// issue-idle. The idle was the per-layer serial weight stage: __syncthreads
// drains vmcnt(0)+lgkmcnt(0), exposing global latency 20x. Now: two static
// LDS weight buffers (parity = li&1, compile-time), async stage via
// global_load_lds width=16 (no VGPR round-trip), raw s_barrier + counted
// "s_waitcnt vmcnt(4)" so the next layer's 4 stage loads stay in flight
// across barriers; their latency hides under the current layer's compute.
// Bias VGPR-prefetch issued BEFORE each stage keeps the vmcnt FIFO clean.
// LDS = 2x16 KB W + 4x4 KB act = 48 KB; 3 blocks/CU.
__global__ __launch_bounds__(256, 3)
void pairs_mlp_kernel(const int* __restrict__ idx_i,
                      const int* __restrict__ idx_j,
                      float* __restrict__ out_rij)       // d_out + 20000 (f32)
{
    __shared__ i4_ma w_lds0[1024];           // 16 KB: even layers
    __shared__ i4_ma w_lds1[1024];           // 16 KB: odd layers
    __shared__ u2_ma act_all[4 * 512];       // 4 waves x (32 rows x 16 chunks of 8B)

    const int wave = threadIdx.x >> 6;
    const int lane = threadIdx.x & 63;
    u2_ma* act = act_all + wave * 512;

    const int pp = lane & 31;           // pair owned (both half-waves mirror)
    const int p0 = blockIdx.x * 128 + wave * 32;
    const int p = p0 + pp;
    const bool valid = (p < NP);

    // ---- phase 0: rij + radial basis, built DIRECTLY into fp8 B-frag regs ----
    int ai = 0, aj = 0;
    if (valid) { ai = idx_i[p]; aj = idx_j[p]; }
    float xi0 = g_Rf[3 * ai + 0], xi1 = g_Rf[3 * ai + 1], xi2 = g_Rf[3 * ai + 2];
    float xj0 = g_Rf[3 * aj + 0], xj1 = g_Rf[3 * aj + 1], xj2 = g_Rf[3 * aj + 2];
    float dx = xj0 - xi0, dy = xj1 - xi1, dz = xj2 - xi2;
    float rij = sqrtf(dx * dx + dy * dy + dz * dz + 1e-12f);
    if (lane < 32 && valid) out_rij[p] = rij;

    float fcut = 0.0f;
    if (valid && rij < 10.0f) {
        float xc = rij * 0.1f;
        float x3 = xc * xc * xc;
        fcut = 1.0f + x3 * (-10.0f + xc * (15.0f - 6.0f * xc));
    }

    const int q = lane >> 4;        // quad
    const int l15 = lane & 15;
    const int aseg = valid ? ai : -1;   // sentinel: invalid pairs never merge/fire

    // ---- prologue prefetch: layers 0,1 weights + layer-0 bias ----
    // (issued after the R/idx consumption above so the vmcnt FIFO stays clean)
    FENCE();
    stage_w(0, w_lds0);
    stage_w(1, w_lds1);
    f32x4 biasv[8];
    load_bias(biasv, 0, q);
    FENCE();

    const float mu0 = 4.5399929762484854e-05f;
    const float dmu = (1.0f - mu0) / 127.0f;
    const float wc = (2.0f / 128.0f) * (1.0f - mu0);
    const float NW2 = -(1.0f / (wc * wc)) * LOG2E;
    float er = FEXP2(-rij * LOG2E);

    // B-frag carry regs: bfrX[nt][kt] = x[pair nt*16+l15][k=kt*32+q*8 .. +7] fp8
    // (radial-basis VALU below also hides the prologue stage latency)
    u2_ma bfrX[2][4];
    {
        float er_n[2], fc_n[2];
        er_n[0] = __shfl(er, l15, 64);      fc_n[0] = __shfl(fcut, l15, 64);
        er_n[1] = __shfl(er, 16 + l15, 64); fc_n[1] = __shfl(fcut, 16 + l15, 64);
#pragma unroll
        for (int nt = 0; nt < 2; ++nt)
#pragma unroll
            for (int kt = 0; kt < 4; ++kt) {
                float v[8];
#pragma unroll
                for (int jj = 0; jj < 8; ++jj) {
                    int g = kt * 32 + q * 8 + jj;
                    float mu = mu0 + (float)g * dmu;
                    float e0 = er_n[nt] - mu;
                    v[jj] = fc_n[nt] * FEXP2(NW2 * e0 * e0);
                }
                int w0 = cvtpk2<false>(v[0], v[1], 0);
                w0 = cvtpk2<true>(v[2], v[3], w0);
                int w1 = cvtpk2<false>(v[4], v[5], 0);
                w1 = cvtpk2<true>(v[6], v[7], w1);
                bfrX[nt][kt].x = (uint_t)w0;
                bfrX[nt][kt].y = (uint_t)w1;
            }
    }

    for (int blk = 0; blk < NBLK; ++blk) {
#pragma unroll
        for (int li = 0; li < 4; ++li) {
            const int L = blk * 4 + li;
            // buffer parity is compile-time (blk*4 is even): even li -> buf0
            const u2_ma* wl2 = (const u2_ma*)((li & 1) ? w_lds1 : w_lds0);
            i4_ma* wbuf = (li & 1) ? w_lds1 : w_lds0;

            // current layer's 4 stage loads (issued 2 iters ago) must be done;
            // next layer's 4 stay in flight. FIFO: bias(L) [8, older] completes
            // too; stage(L+1) [4, youngest] survives.
            asm volatile("s_waitcnt vmcnt(4)" ::: "memory");
            __builtin_amdgcn_s_barrier();     // all waves' stages landed
            FENCE();

            // acc initialized to folded bias (b*log2e - 1), from prefetched regs
            f32x4 acc[2][8];
#pragma unroll
            for (int mt = 0; mt < 8; ++mt) {
                acc[0][mt] = biasv[mt];
                acc[1][mt] = biasv[mt];
            }
#pragma unroll
            for (int kt = 0; kt < 4; ++kt) {
                const int cc = kt * 4 + q;
                u2_ma b0, b1;
                if (li == 0) {
                    b0 = bfrX[0][kt];
                    b1 = bfrX[1][kt];
                } else {
                    b0 = act[(l15) * 16 + (cc ^ l15)];
                    b1 = act[(16 + l15) * 16 + (cc ^ l15)];
                    if (li == 2) { bfrX[0][kt] = b0; bfrX[1][kt] = b1; }  // carry x
                }
                const long lb0 = u2l(b0), lb1 = u2l(b1);
#pragma unroll
                for (int mt = 0; mt < 8; ++mt) {
                    const long la = u2l(wl2[(mt * 16 + l15) * 16 + (cc ^ l15)]);
                    acc[0][mt] = __builtin_amdgcn_mfma_f32_16x16x32_fp8_fp8(
                        la, lb0, acc[0][mt], 0, 0, 0);
                    acc[1][mt] = __builtin_amdgcn_mfma_f32_16x16x32_fp8_fp8(
                        la, lb1, acc[1][mt], 0, 0, 0);
                }
            }

            if (li < 3) {
                // ssp + fp8 pack + in-place LDS write (wave-private region; all
                // this layer's act ds_reads precede these writes in program order)
#pragma unroll
                for (int mt = 0; mt < 8; ++mt) {
                    const int c = mt * 2 + (q >> 1);   // feature chunk (8 fp8)
#pragma unroll
                    for (int nt = 0; nt < 2; ++nt) {
                        float u0 = ssp_u(acc[nt][mt][0]);
                        float u1 = ssp_u(acc[nt][mt][1]);
                        float u2 = ssp_u(acc[nt][mt][2]);
                        float u3 = ssp_u(acc[nt][mt][3]);
                        int w = cvtpk2<false>(u0, u1, 0);
                        w = cvtpk2<true>(u2, u3, w);
                        const int rp = nt * 16 + l15;
                        ((u1_ma*)&act[rp * 16 + (c ^ (rp & 15))])[q & 1] = (uint_t)w;
                    }
                }
            } else {
                // head: out_e = u3 @ (ln2*oWf) + oBf, then sorted-segment reduction
                const float* hw = g_oWfF + blk * 256;
                const float ob0 = g_oBfF[blk * 2 + 0];
                const float ob1 = g_oBfF[blk * 2 + 1];
                float hs[2][2];
#pragma unroll
                for (int nt = 0; nt < 2; ++nt) {
                    float h0 = 0.f, h1 = 0.f;
#pragma unroll
                    for (int mt = 0; mt < 8; ++mt) {
#pragma unroll
                        for (int rr = 0; rr < 4; ++rr) {
                            float u = ssp_u(acc[nt][mt][rr]);
                            const int f = mt * 16 + q * 4 + rr;
                            h0 = fmaf(u, hw[f * 2 + 0], h0);
                            h1 = fmaf(u, hw[f * 2 + 1], h1);
                        }
                    }
                    h0 += __shfl_xor(h0, 16, 64);
                    h0 += __shfl_xor(h0, 32, 64);
                    h1 += __shfl_xor(h1, 16, 64);
                    h1 += __shfl_xor(h1, 32, 64);
                    hs[nt][0] = h0; hs[nt][1] = h1;
                }
                float c0v = (pp < 16) ? hs[0][0] : hs[1][0];
                float c1v = (pp < 16) ? hs[0][1] : hs[1][1];
                c0v += ob0; c1v += ob1;
                // segmented inclusive scan over the 32 sorted pairs (runs contiguous)
#pragma unroll
                for (int d = 1; d < 32; d <<= 1) {
                    float t0 = __shfl_up(c0v, d, 64);
                    float t1 = __shfl_up(c1v, d, 64);
                    int   an = __shfl_up(aseg, d, 64);
                    if (pp >= d && an == aseg) { c0v += t0; c1v += t1; }
                }
                int ain = __shfl_down(aseg, 1, 64);
                bool tail = (pp == 31) || (ain != aseg);
                if (lane < 32 && valid && tail) {
                    atomicAdd(&g_outs[(blk * NA + aseg) * 2 + 0], c0v);
                    atomicAdd(&g_outs[(blk * NA + aseg) * 2 + 1], c1v);
                }
            }

            // ---- tail: bias(L+1) prefetch, then barrier, then stage(L+2) ----
            // bias loads BEFORE stage keeps FIFO order {bias older, stage newer}
            {
                int Lb = L + 1; if (Lb >= NL) Lb = 0;
                load_bias(biasv, Lb, q);
                FENCE();
            }
            __builtin_amdgcn_s_barrier();     // all waves done READING wbuf
            FENCE();
            {
                int Ls = L + 2; if (Ls >= NL) Ls -= NL;   // wraparound: uniform vmcnt
                stage_w(Ls, wbuf);
                FENCE();
            }
        }
    }
}

// ---------------- finalize: scale/shift + nhloss (last-block writes nh) ----------
__global__ void finalize_kernel(const int* __restrict__ Z,
                                float* __restrict__ out_atoms,   // d_out (f32)
                                float* __restrict__ out_nh)
{
    __shared__ float red[256];
    const int a = blockIdx.x * 256 + threadIdx.x;
    float s = 0.f;
    if (a < NA) {
        float v[NBLK][2];
        float t0 = 0.f, t1 = 0.f;
#pragma unroll
        for (int b = 0; b < NBLK; ++b) {
            v[b][0] = g_outs[(b * NA + a) * 2 + 0];
            v[b][1] = g_outs[(b * NA + a) * 2 + 1];
            t0 += v[b][0]; t1 += v[b][1];
        }
        const int z = Z[a];
        out_atoms[a * 2 + 0] = t0 * g_scF[z]      + g_shF[z];
        out_atoms[a * 2 + 1] = t1 * g_scF[95 + z] + g_shF[95 + z];
#pragma unroll
        for (int b = 1; b < NBLK; ++b)
#pragma unroll
            for (int o = 0; o < 2; ++o) {
                float x2 = v[b][o] * v[b][o];
                float p2 = v[b - 1][o] * v[b - 1][o];
                s += x2 / (x2 + p2 + 1e-7f);
            }
    }
    red[threadIdx.x] = s;
    __syncthreads();
    for (int st = 128; st > 0; st >>= 1) {
        if (threadIdx.x < st) red[threadIdx.x] += red[threadIdx.x + st];
        __syncthreads();
    }
    if (threadIdx.x == 0) {
        atomicAdd(&g_nh[0], red[0]);
        __threadfence();
        unsigned old = atomicAdd(&g_done, 1u);
        if (old == gridDim.x - 1) {
            float v = atomicAdd(&g_nh[0], 0.0f);   // device-scope coherent read
            out_nh[0] = v * (1.0f / 20000.0f);
        }
    }
}

// ---------------- launch ----------------
extern "C" void kernel_launch(void* const* d_in, const int* in_sizes, int n_in,
                              void* d_out, int out_size, void* d_ws, size_t ws_size,
                              hipStream_t stream)
{
    const int* Z     = (const int*)d_in[0];
    const void* R    = d_in[1];
    const int* idx_i = (const int*)d_in[2];
    const int* idx_j = (const int*)d_in[3];
    const void* iW   = d_in[4];
    const void* iB   = d_in[5];
    const void* oW   = d_in[6];
    const void* oB   = d_in[7];
    const void* oWf  = d_in[8];
    const void* oBf  = d_in[9];
    const void* scales = d_in[10];
    const void* shifts = d_in[11];

    float* out_f = (float*)d_out;   // [0,20000): outputs  [20000,270000): rij  [270000]: nhloss

    prep_kernel<<<80 + 391, 256, 0, stream>>>(iW, iB, oW, oB, R, oWf, oBf, scales, shifts);
    pairs_mlp_kernel<<<(NP + 127) / 128, 256, 0, stream>>>(idx_i, idx_j, out_f + 2 * NA);
    finalize_kernel<<<(NA + 255) / 256, 256, 0, stream>>>(Z, out_f, out_f + 2 * NA + NP);
}